// Round 12
// baseline (647.711 us; speedup 1.0000x reference)
//
#include <hip/hip_runtime.h>
#include <math.h>

// entmax-1.5 rows of 4096 x 32000 f32.
// Round-12 = round-6 pipeline skeleton (246 us, verified) with stats()
// restructured to ONE block barrier per row:
//  - wave-local threshold (wavemax_w - 2): since wavemax_w <= xmax, the
//    gathered set is a SUPERSET of the true candidate set {x > xmax-2}
//    (tau* in [-1,0) on the z=(x-xmax)/2 scale). Raw x is gathered; z is
//    computed on the fly in the solve once xmax is known. Removes the
//    block-max barrier.
//  - per-wave LDS segments s_cand[parity][wave][256]: no s_total atomic,
//    no cross-wave scan. Double-buffered by row parity: wave w's write of
//    seg(w,p) for row r+2 happens after barrier(r+1); any wave's solve-read
//    of seg(w,p) for row r happens before it arrives at barrier(r+1) ->
//    barrier(r+1) separates them. SAFE.
//  - ALL-WAVE redundant solve: every wave computes bit-identical tau from
//    identical LDS data -> no tau broadcast, no post-solve barrier; waves
//    stagger freely into transform/store/prefetch. Idle-wave time becomes
//    (redundant) parallel compute.
// Pipeline (unchanged from round 6): depth-2 ping-pong A/B, asm-pinned
// global_load_dwordx4, stores-then-prefetch-then-vmcnt(16). Wave-uniform
// FIFO note: waves 13-15 skip their 8th store (idx>=ROWV4) AND their 8th
// load is the clamped dummy whose value is never consumed -> vmcnt(16)
// leaving that one load unretired is sound (round-6 property, preserved).

#define ROWLEN 32000
#define ROWV4  8000
#define BLOCK  1024
#define NV4    8              // 8 float4 per thread
#define NW     16             // waves per block
#define SEGCAP 256            // per-wave candidate cap (~136 expected, +11sig)
#define GRID   256

typedef float f32x4 __attribute__((ext_vector_type(4)));

__device__ __forceinline__ void wg_barrier() {
  // LDS-visibility barrier that does NOT drain vmcnt (prefetch stays live).
  asm volatile("s_waitcnt lgkmcnt(0)" ::: "memory");
  __builtin_amdgcn_sched_barrier(0);
  __builtin_amdgcn_s_barrier();
  __builtin_amdgcn_sched_barrier(0);
}

__device__ __forceinline__ void wait_vm8() {
  asm volatile("s_waitcnt vmcnt(8)" ::: "memory");
  __builtin_amdgcn_sched_barrier(0);   // rule #18
}
__device__ __forceinline__ void wait_vm16() {
  asm volatile("s_waitcnt vmcnt(16)" ::: "memory");
  __builtin_amdgcn_sched_barrier(0);   // rule #18
}

__device__ __forceinline__ void issue_row(f32x4 (&v)[NV4],
                                          const float* __restrict__ rowp,
                                          int t) {
#pragma unroll
  for (int i = 0; i < NV4; ++i) {
    int idx = i * BLOCK + t;
    idx = idx < ROWV4 ? idx : 0;           // clamp: OOB lanes reload elem 0
    const float* p = rowp + (size_t)idx * 4;
    asm volatile("global_load_dwordx4 %0, %1, off"
                 : "=&v"(v[i]) : "v"(p) : "memory");
  }
}

__global__ __launch_bounds__(BLOCK)
void entmax15_kernel(const float* __restrict__ x, float* __restrict__ out,
                     int rows, int rpb) {
  const int t    = threadIdx.x;
  const int lane = t & 63;
  const int wid  = t >> 6;

  __shared__ float s_cand[2][NW][SEGCAP];
  __shared__ float s_wmax[2][NW];
  __shared__ int   s_wcnt[2][NW];

  const int rbeg = blockIdx.x * rpb;
  const int rend = min(rbeg + rpb, rows);
  if (rbeg >= rend) return;

  f32x4 A[NV4], B[NV4];

  // ---- stats + all-wave tau solve: ONE barrier. returns cc ----
  auto stats = [&](f32x4 (&v)[NV4], int par) -> float {
    // wave-local max (regs + shfl only)
    float lmax = -1e30f;
#pragma unroll
    for (int i = 0; i < NV4; ++i) {
      int idx = i * BLOCK + t;
      if (idx < ROWV4)
        lmax = fmaxf(lmax,
                     fmaxf(fmaxf(v[i].x, v[i].y), fmaxf(v[i].z, v[i].w)));
    }
#pragma unroll
    for (int m = 32; m >= 1; m >>= 1) lmax = fmaxf(lmax, __shfl_xor(lmax, m));
    const float thr = lmax - 2.0f;        // wave-local superset threshold

    // per-thread count + intra-wave scan
    int c = 0;
#pragma unroll
    for (int i = 0; i < NV4; ++i) {
      int idx = i * BLOCK + t;
      if (idx < ROWV4)
        c += (v[i].x > thr) + (v[i].y > thr) + (v[i].z > thr) + (v[i].w > thr);
    }
    int incl = c;
#pragma unroll
    for (int m = 1; m < 64; m <<= 1) {
      int nb = __shfl_up(incl, m);
      if (lane >= m) incl += nb;
    }

    // gather RAW x into my wave's segment (no atomics, no cross-wave scan)
    {
      float* seg = &s_cand[par][wid][0];
      int off = incl - c;
#pragma unroll
      for (int i = 0; i < NV4; ++i) {
        int idx = i * BLOCK + t;
        if (idx < ROWV4) {
          float a;
          a = v[i].x; if (a > thr) { if (off < SEGCAP) seg[off] = a; ++off; }
          a = v[i].y; if (a > thr) { if (off < SEGCAP) seg[off] = a; ++off; }
          a = v[i].z; if (a > thr) { if (off < SEGCAP) seg[off] = a; ++off; }
          a = v[i].w; if (a > thr) { if (off < SEGCAP) seg[off] = a; ++off; }
        }
      }
    }
    if (lane == 63) {
      s_wcnt[par][wid] = min(incl, SEGCAP);
      s_wmax[par][wid] = lmax;
    }
    wg_barrier();                        // THE one barrier per row

    // global max from the 16 wave maxes (LDS broadcast reads)
    float xmax = s_wmax[par][0];
#pragma unroll
    for (int w = 1; w < NW; ++w) xmax = fmaxf(xmax, s_wmax[par][w]);

    // ---- every wave solves tau redundantly (bit-identical) ----
    float tau = -1.0f;
    for (int it = 0; it < 6; ++it) {     // Newton, monotone from the left
      float s = 0.f, q = 0.f;
#pragma unroll 1
      for (int w2 = 0; w2 < NW; ++w2) {
        int cnt = __builtin_amdgcn_readfirstlane(s_wcnt[par][w2]);
        const float* sg = &s_cand[par][w2][0];
        for (int j = lane; j < cnt; j += 64) {
          float d = fmaf(sg[j] - xmax, 0.5f, -tau);  // z - tau
          if (d > 0.f) { s += d; q += d * d; }
        }
      }
#pragma unroll
      for (int m = 32; m >= 1; m >>= 1) {
        s += __shfl_xor(s, m);
        q += __shfl_xor(q, m);
      }
      if (s > 0.f) tau += (q - 1.0f) / (2.0f * s);
    }
    for (int it = 0; it < 2; ++it) {     // closed-form support fix-point
      float kk = 0.f, s1 = 0.f, s2 = 0.f;
#pragma unroll 1
      for (int w2 = 0; w2 < NW; ++w2) {
        int cnt = __builtin_amdgcn_readfirstlane(s_wcnt[par][w2]);
        const float* sg = &s_cand[par][w2][0];
        for (int j = lane; j < cnt; j += 64) {
          float z = (sg[j] - xmax) * 0.5f;
          if (z > tau) { kk += 1.f; s1 += z; s2 += z * z; }
        }
      }
#pragma unroll
      for (int m = 32; m >= 1; m >>= 1) {
        kk += __shfl_xor(kk, m);
        s1 += __shfl_xor(s1, m);
        s2 += __shfl_xor(s2, m);
      }
      float disc = s1 * s1 - kk * (s2 - 1.0f);
      tau = (s1 - sqrtf(fmaxf(disc, 0.f))) / kk;
    }
    return fmaf(xmax, 0.5f, tau);        // p = max(x*0.5 - cc, 0)^2
  };

  // process: stats -> transform -> stores (round-6 order, untouched)
  auto process = [&](f32x4 (&v)[NV4], int row) {
    const float cc = stats(v, row & 1);
    f32x4* __restrict__ outr = (f32x4*)(out + (size_t)row * ROWLEN);
#pragma unroll
    for (int i = 0; i < NV4; ++i) {
      int idx = i * BLOCK + t;
      if (idx < ROWV4) {
        f32x4 o;
        float d;
        d = fmaf(v[i].x, 0.5f, -cc); o.x = d > 0.f ? d * d : 0.f;
        d = fmaf(v[i].y, 0.5f, -cc); o.y = d > 0.f ? d * d : 0.f;
        d = fmaf(v[i].z, 0.5f, -cc); o.z = d > 0.f ? d * d : 0.f;
        d = fmaf(v[i].w, 0.5f, -cc); o.w = d > 0.f ? d * d : 0.f;
        outr[idx] = o;
      }
    }
  };

  // ---- depth-2 pipeline (round-6 skeleton, verbatim) ----
  issue_row(A, x + (size_t)rbeg * ROWLEN, t);
  {
    int rB0 = (rbeg + 1 < rend) ? rbeg + 1 : rbeg;
    issue_row(B, x + (size_t)rB0 * ROWLEN, t);
  }
  wait_vm8();                              // prologue: only 16 loads out
  for (int r = rbeg; r < rend; r += 2) {
    process(A, r);                         // ends with row-r stores (newest)
    {
      int rn = (r + 2 < rend) ? r + 2 : rend - 1;
      issue_row(A, x + (size_t)rn * ROWLEN, t);
    }
    wait_vm16();                           // B-loads retired; stores in flight
    if (r + 1 >= rend) break;
    process(B, r + 1);
    {
      int rn = (r + 3 < rend) ? r + 3 : rend - 1;
      issue_row(B, x + (size_t)rn * ROWLEN, t);
    }
    wait_vm16();                           // A-loads retired; stores in flight
  }
}

extern "C" void kernel_launch(void* const* d_in, const int* in_sizes, int n_in,
                              void* d_out, int out_size, void* d_ws, size_t ws_size,
                              hipStream_t stream) {
  const float* x = (const float*)d_in[0];
  float* out = (float*)d_out;
  int rows = in_sizes[0] / ROWLEN;
  int grid = rows < GRID ? rows : GRID;
  int rpb  = (rows + grid - 1) / grid;
  hipLaunchKernelGGL(entmax15_kernel, dim3(grid), dim3(BLOCK), 0, stream,
                     x, out, rows, rpb);
}

// Round 13
// 251.887 us; speedup vs baseline: 2.5714x; 2.5714x over previous
//
#include <hip/hip_runtime.h>
#include <math.h>
#include <stdint.h>

// entmax-1.5 rows of 4096 x 32000 f32.
// Round-13: LDS-resident row + async global_load_lds prefetch.
//  - Row staged into 128KB LDS via __builtin_amdgcn_global_load_lds (16B
//    width). NO destination VGPRs -> the store-data WAR hazard that forced
//    protective vmcnt stalls in rounds 5-11 is structurally impossible.
//  - Prefetch of row r+1 issues ~25% into row r (right after LDS->reg copy
//    frees the buffer) and drains asynchronously under gather/solve/
//    transform -> HBM busy through the serial phases (the 5us/row idle gap
//    at 246us).
//  - Per-wave chunk = 500 f32x4 (16x500 = 8000 = full row), staged as 8
//    blocks of 64 lanes (512 slots; 12 dup lanes clamp to chunk start ->
//    benign identical-value duplicate stores, excluded from stats).
//  - Per-wave VMEM FIFO per row: [8 gl_lds][8 stores], uniform across all
//    waves. Bottom-of-loop vmcnt(8) retires the prefetch, keeps stores in
//    flight (they drain under the next row's pass1/barrier).
//  - stats/solve = round-6 verified math: 3 barriers, wave0 solve over
//    candidates {x > xmax-2} (tau* in [-1,0] on z=(x-xmax)/2 scale).

#define ROWLEN 32000
#define BLOCK  1024
#define NW     16
#define CHUNK  500            // f32x4 per wave; 16*500 = 8000 = row
#define NB     8              // staged 64-lane blocks per wave (512 slots)
#define CAND_MAX 2048
#define GRID   256

typedef float f32x4 __attribute__((ext_vector_type(4)));
typedef __attribute__((address_space(1))) const void gvoid;
typedef __attribute__((address_space(3))) void lvoid;

__device__ __forceinline__ void wg_barrier() {
  asm volatile("s_waitcnt lgkmcnt(0)" ::: "memory");
  __builtin_amdgcn_sched_barrier(0);
  __builtin_amdgcn_s_barrier();
  __builtin_amdgcn_sched_barrier(0);
}
__device__ __forceinline__ void wait_vm0() {
  asm volatile("s_waitcnt vmcnt(0)" ::: "memory");
  __builtin_amdgcn_sched_barrier(0);
}
__device__ __forceinline__ void wait_vm8() {
  asm volatile("s_waitcnt vmcnt(8)" ::: "memory");
  __builtin_amdgcn_sched_barrier(0);
}
__device__ __forceinline__ void wait_lgkm0() {
  asm volatile("s_waitcnt lgkmcnt(0)" ::: "memory");
  __builtin_amdgcn_sched_barrier(0);
}

__global__ __launch_bounds__(BLOCK)
void entmax15_kernel(const float* __restrict__ x, float* __restrict__ out,
                     int rows, int rpb) {
  const int t    = threadIdx.x;
  const int lane = t & 63;
  const int wid  = t >> 6;

  __shared__ f32x4 s_row[NW * NB * 64];   // 8192 * 16B = 128 KB
  __shared__ float s_max[NW];
  __shared__ int   s_total;
  __shared__ float s_tau;
  __shared__ float s_cand[CAND_MAX];      // 8 KB

  const int rbeg = blockIdx.x * rpb;
  const int rend = min(rbeg + rpb, rows);
  if (rbeg >= rend) return;

  // async stage of one row into this wave's private LDS chunk
  auto stage = [&](int row) {
    const float* rowp = x + (size_t)row * ROWLEN;
#pragma unroll
    for (int i = 0; i < NB; ++i) {
      int l = i * 64 + lane;
      int e = wid * CHUNK + (l < CHUNK ? l : 0);   // dup lanes clamp to start
      const float* g = rowp + (size_t)e * 4;
      f32x4* d = &s_row[(wid * NB + i) * 64];      // wave-uniform base
      __builtin_amdgcn_global_load_lds((gvoid*)g, (lvoid*)d, 16, 0, 0);
    }
  };

  stage(rbeg);
  wait_vm0();                                      // first chunk resident

  for (int r = rbeg; r < rend; ++r) {
    if (t == 0) s_total = 0;

    // ---- pass1: wave max from LDS (dup values harmless for max) ----
    float lmax = -1e30f;
#pragma unroll
    for (int i = 0; i < NB; ++i) {
      f32x4 u = s_row[(wid * NB + i) * 64 + lane];
      lmax = fmaxf(lmax, fmaxf(fmaxf(u.x, u.y), fmaxf(u.z, u.w)));
    }
#pragma unroll
    for (int m = 32; m >= 1; m >>= 1) lmax = fmaxf(lmax, __shfl_xor(lmax, m));
    if (lane == 0) s_max[wid] = lmax;
    wg_barrier();                         // #1 (covers s_total=0)
    float xmax = s_max[0];
#pragma unroll
    for (int w = 1; w < NW; ++w) xmax = fmaxf(xmax, s_max[w]);
    const float thr = xmax - 2.0f;        // z > -1  <=>  x > xmax-2

    // ---- pass2: LDS -> regs; chunk becomes free ----
    f32x4 v[NB];
#pragma unroll
    for (int i = 0; i < NB; ++i) v[i] = s_row[(wid * NB + i) * 64 + lane];
    wait_lgkm0();                         // reads landed; LDS chunk free

    // ---- async prefetch next row (drains under solve/transform) ----
    stage(r + 1 < rend ? r + 1 : rend - 1);

    // ---- candidates from regs (dup lanes excluded) ----
    int c = 0;
#pragma unroll
    for (int i = 0; i < NB; ++i) {
      int l = i * 64 + lane;
      if (l < CHUNK)
        c += (v[i].x > thr) + (v[i].y > thr) + (v[i].z > thr) + (v[i].w > thr);
    }
    int incl = c;
#pragma unroll
    for (int m = 1; m < 64; m <<= 1) {
      int nb2 = __shfl_up(incl, m);
      if (lane >= m) incl += nb2;
    }
    int wbase = 0;
    if (lane == 63) wbase = atomicAdd(&s_total, incl);
    wbase = __shfl(wbase, 63);
    {
      int off = wbase + incl - c;
#pragma unroll
      for (int i = 0; i < NB; ++i) {
        int l = i * 64 + lane;
        if (l < CHUNK) {
          float a;
          a = v[i].x; if (a > thr) { if (off < CAND_MAX) s_cand[off] = (a - xmax) * 0.5f; ++off; }
          a = v[i].y; if (a > thr) { if (off < CAND_MAX) s_cand[off] = (a - xmax) * 0.5f; ++off; }
          a = v[i].z; if (a > thr) { if (off < CAND_MAX) s_cand[off] = (a - xmax) * 0.5f; ++off; }
          a = v[i].w; if (a > thr) { if (off < CAND_MAX) s_cand[off] = (a - xmax) * 0.5f; ++off; }
        }
      }
    }
    wg_barrier();                         // #2: candidates + total final
    const int total = min(s_total, CAND_MAX);   // tail beyond is ~e^-26

    // ---- tau solve in wave 0 only (round-6 verified math) ----
    if (wid == 0) {
      float tau = -1.0f;
      const int ng = (total + 511) >> 9;  // groups of 8 x 64 lanes
      for (int it = 0; it < 6; ++it) {    // Newton, monotone from the left
        float s = 0.f, q = 0.f;
        for (int g = 0; g < ng; ++g) {
#pragma unroll
          for (int k = 0; k < 8; ++k) {
            int j = lane + ((g << 3) + k) * 64;
            float z = s_cand[j & (CAND_MAX - 1)];
            float d = z - tau;
            if (j < total && d > 0.f) { s += d; q += d * d; }
          }
        }
#pragma unroll
        for (int m = 32; m >= 1; m >>= 1) {
          s += __shfl_xor(s, m);
          q += __shfl_xor(q, m);
        }
        if (s > 0.f) tau += (q - 1.0f) / (2.0f * s);
      }
      for (int it = 0; it < 2; ++it) {    // closed-form support fix-point
        float kk = 0.f, s1 = 0.f, s2 = 0.f;
        for (int g = 0; g < ng; ++g) {
#pragma unroll
          for (int k = 0; k < 8; ++k) {
            int j = lane + ((g << 3) + k) * 64;
            float z = s_cand[j & (CAND_MAX - 1)];
            if (j < total && z > tau) { kk += 1.f; s1 += z; s2 += z * z; }
          }
        }
#pragma unroll
        for (int m = 32; m >= 1; m >>= 1) {
          kk += __shfl_xor(kk, m);
          s1 += __shfl_xor(s1, m);
          s2 += __shfl_xor(s2, m);
        }
        float disc = s1 * s1 - kk * (s2 - 1.0f);
        tau = (s1 - sqrtf(fmaxf(disc, 0.f))) / kk;
      }
      if (lane == 0) s_tau = tau;
    }
    wg_barrier();                         // #3: tau ready
    const float cc = fmaf(xmax, 0.5f, s_tau);   // p = max(x*0.5 - cc, 0)^2

    // ---- transform + store (dup lanes write identical value to e=start) ----
    f32x4* __restrict__ outv = (f32x4*)(out + (size_t)r * ROWLEN);
#pragma unroll
    for (int i = 0; i < NB; ++i) {
      int l = i * 64 + lane;
      int e = wid * CHUNK + (l < CHUNK ? l : 0);
      f32x4 o;
      float d;
      d = fmaf(v[i].x, 0.5f, -cc); o.x = d > 0.f ? d * d : 0.f;
      d = fmaf(v[i].y, 0.5f, -cc); o.y = d > 0.f ? d * d : 0.f;
      d = fmaf(v[i].z, 0.5f, -cc); o.z = d > 0.f ? d * d : 0.f;
      d = fmaf(v[i].w, 0.5f, -cc); o.w = d > 0.f ? d * d : 0.f;
      outv[e] = o;
    }

    // FIFO: [gl_lds next (8, oldest)][stores r (8, newest)]
    wait_vm8();                           // next chunk resident; stores fly
  }
}

extern "C" void kernel_launch(void* const* d_in, const int* in_sizes, int n_in,
                              void* d_out, int out_size, void* d_ws, size_t ws_size,
                              hipStream_t stream) {
  const float* x = (const float*)d_in[0];
  float* out = (float*)d_out;
  int rows = in_sizes[0] / ROWLEN;
  int grid = rows < GRID ? rows : GRID;
  int rpb  = (rows + grid - 1) / grid;
  hipLaunchKernelGGL(entmax15_kernel, dim3(grid), dim3(BLOCK), 0, stream,
                     x, out, rows, rpb);
}

// Round 14
// 234.296 us; speedup vs baseline: 2.7645x; 1.0751x over previous
//
#include <hip/hip_runtime.h>
#include <math.h>

// entmax-1.5 rows of 4096 x 32000 f32.
// Round-14: ONE ROW PER 256-THREAD BLOCK, grid=4096, row in registers.
// Rationale: rounds 5-13 (reg pipeline / 2-block / LDS-async) all plateau at
// 246-252 us because a single barrier-synced 16-wave block per CU exposes the
// per-row serial chain (max -> gather -> wave0 solve, ~5us) against a 10.4us
// BW share with nothing independent to overlap. Here ~160 VGPR/thread ->
// 3 waves/SIMD -> THREE independent blocks (=rows) per CU: one block's
// solve/barrier phases overlap the other two blocks' streaming. No asm
// pipelining, no hand-counted vmcnt (nothing to protect): plain loads/stores,
// __syncthreads, compiler-inserted waits. TLP does the hiding.
// Gather uses wave-local threshold (wavemax_w - 2): since wavemax_w <= xmax,
// the union over waves is a SUPERSET of {x > xmax-2} (tau* in [-1,0] on the
// z=(x-xmax)/2 scale); extras are inert because every solve term filters
// z - tau > 0 with the exact xmax. Solve = wave0 only (round-12's regression
// was the 16x redundant solve, not this gather).

#define ROWLEN 32000
#define ROWV4  8000
#define BLOCK  256
#define NWAVE  4
#define NV     31             // full iterations; +1 partial (t<64)
#define SEGCAP 768            // per-wave candidate cap (mean ~400, >15 sigma)

typedef float f32x4 __attribute__((ext_vector_type(4)));

__global__ __launch_bounds__(BLOCK, 3)   // cap VGPR ~170: row fits in regs
void entmax15_kernel(const float* __restrict__ x, float* __restrict__ out,
                     int rows) {
  const int row = blockIdx.x;
  if (row >= rows) return;
  const int t    = threadIdx.x;
  const int lane = t & 63;
  const int wid  = t >> 6;

  __shared__ float s_wmax[NWAVE];
  __shared__ int   s_cnt[NWAVE];
  __shared__ float s_tau;
  __shared__ float s_seg[NWAVE][SEGCAP];

  const f32x4* __restrict__ xr = (const f32x4*)(x + (size_t)row * ROWLEN);

  // ---- load full row into registers (31 full + 1 partial vector) ----
  f32x4 v[NV];
  f32x4 vtail;
#pragma unroll
  for (int i = 0; i < NV; ++i) v[i] = xr[i * BLOCK + t];
  vtail = xr[(t < 64) ? (NV * BLOCK + t) : t];   // t>=64: benign dup of elem t

  // ---- wave max (dup in vtail harmless for max) ----
  float lmax = -1e30f;
#pragma unroll
  for (int i = 0; i < NV; ++i)
    lmax = fmaxf(lmax, fmaxf(fmaxf(v[i].x, v[i].y), fmaxf(v[i].z, v[i].w)));
  lmax = fmaxf(lmax, fmaxf(fmaxf(vtail.x, vtail.y), fmaxf(vtail.z, vtail.w)));
#pragma unroll
  for (int m = 32; m >= 1; m >>= 1) lmax = fmaxf(lmax, __shfl_xor(lmax, m));
  const float thr = lmax - 2.0f;          // wave-local superset threshold

  // ---- count candidates (exclude dup lanes in tail) ----
  int c = 0;
#pragma unroll
  for (int i = 0; i < NV; ++i)
    c += (v[i].x > thr) + (v[i].y > thr) + (v[i].z > thr) + (v[i].w > thr);
  if (t < 64)
    c += (vtail.x > thr) + (vtail.y > thr) + (vtail.z > thr) + (vtail.w > thr);

  // wave inclusive scan
  int incl = c;
#pragma unroll
  for (int m = 1; m < 64; m <<= 1) {
    int nb = __shfl_up(incl, m);
    if (lane >= m) incl += nb;
  }

  // ---- gather raw x into my wave's segment ----
  {
    float* seg = &s_seg[wid][0];
    int off = incl - c;
    float a;
#pragma unroll
    for (int i = 0; i < NV; ++i) {
      a = v[i].x; if (a > thr) { if (off < SEGCAP) seg[off] = a; ++off; }
      a = v[i].y; if (a > thr) { if (off < SEGCAP) seg[off] = a; ++off; }
      a = v[i].z; if (a > thr) { if (off < SEGCAP) seg[off] = a; ++off; }
      a = v[i].w; if (a > thr) { if (off < SEGCAP) seg[off] = a; ++off; }
    }
    if (t < 64) {
      a = vtail.x; if (a > thr) { if (off < SEGCAP) seg[off] = a; ++off; }
      a = vtail.y; if (a > thr) { if (off < SEGCAP) seg[off] = a; ++off; }
      a = vtail.z; if (a > thr) { if (off < SEGCAP) seg[off] = a; ++off; }
      a = vtail.w; if (a > thr) { if (off < SEGCAP) seg[off] = a; ++off; }
    }
  }
  if (lane == 63) {
    s_cnt[wid]  = min(incl, SEGCAP);
    s_wmax[wid] = lmax;
  }
  __syncthreads();                        // barrier 1: segs + maxes ready

  // ---- wave0 solves tau over the 4 segments ----
  if (wid == 0) {
    float xmax = fmaxf(fmaxf(s_wmax[0], s_wmax[1]),
                       fmaxf(s_wmax[2], s_wmax[3]));
    float tau = -1.0f;
    for (int it = 0; it < 6; ++it) {      // Newton from the left (monotone)
      float s = 0.f, q = 0.f;
#pragma unroll 1
      for (int w2 = 0; w2 < NWAVE; ++w2) {
        const int cnt = s_cnt[w2];
        const float* sg = &s_seg[w2][0];
        for (int j = lane; j < cnt; j += 64) {
          float d = fmaf(sg[j] - xmax, 0.5f, -tau);   // z - tau
          if (d > 0.f) { s += d; q += d * d; }
        }
      }
#pragma unroll
      for (int m = 32; m >= 1; m >>= 1) {
        s += __shfl_xor(s, m);
        q += __shfl_xor(q, m);
      }
      if (s > 0.f) tau += (q - 1.0f) / (2.0f * s);
    }
    for (int it = 0; it < 2; ++it) {      // closed-form support fix-point
      float kk = 0.f, s1 = 0.f, s2 = 0.f;
#pragma unroll 1
      for (int w2 = 0; w2 < NWAVE; ++w2) {
        const int cnt = s_cnt[w2];
        const float* sg = &s_seg[w2][0];
        for (int j = lane; j < cnt; j += 64) {
          float z = (sg[j] - xmax) * 0.5f;
          if (z > tau) { kk += 1.f; s1 += z; s2 += z * z; }
        }
      }
#pragma unroll
      for (int m = 32; m >= 1; m >>= 1) {
        kk += __shfl_xor(kk, m);
        s1 += __shfl_xor(s1, m);
        s2 += __shfl_xor(s2, m);
      }
      float disc = s1 * s1 - kk * (s2 - 1.0f);
      tau = (s1 - sqrtf(fmaxf(disc, 0.f))) / kk;
    }
    if (lane == 0) s_tau = fmaf(xmax, 0.5f, tau);   // cc
  }
  __syncthreads();                        // barrier 2: cc ready
  const float cc = s_tau;                 // p = max(x*0.5 - cc, 0)^2

  // ---- transform + store straight from registers ----
  f32x4* __restrict__ outr = (f32x4*)(out + (size_t)row * ROWLEN);
  float d;
#pragma unroll
  for (int i = 0; i < NV; ++i) {
    f32x4 o;
    d = fmaf(v[i].x, 0.5f, -cc); o.x = d > 0.f ? d * d : 0.f;
    d = fmaf(v[i].y, 0.5f, -cc); o.y = d > 0.f ? d * d : 0.f;
    d = fmaf(v[i].z, 0.5f, -cc); o.z = d > 0.f ? d * d : 0.f;
    d = fmaf(v[i].w, 0.5f, -cc); o.w = d > 0.f ? d * d : 0.f;
    outr[i * BLOCK + t] = o;
  }
  if (t < 64) {
    f32x4 o;
    d = fmaf(vtail.x, 0.5f, -cc); o.x = d > 0.f ? d * d : 0.f;
    d = fmaf(vtail.y, 0.5f, -cc); o.y = d > 0.f ? d * d : 0.f;
    d = fmaf(vtail.z, 0.5f, -cc); o.z = d > 0.f ? d * d : 0.f;
    d = fmaf(vtail.w, 0.5f, -cc); o.w = d > 0.f ? d * d : 0.f;
    outr[NV * BLOCK + t] = o;
  }
}

extern "C" void kernel_launch(void* const* d_in, const int* in_sizes, int n_in,
                              void* d_out, int out_size, void* d_ws, size_t ws_size,
                              hipStream_t stream) {
  const float* x = (const float*)d_in[0];
  float* out = (float*)d_out;
  int rows = in_sizes[0] / ROWLEN;
  hipLaunchKernelGGL(entmax15_kernel, dim3(rows), dim3(BLOCK), 0, stream,
                     x, out, rows);
}